// Round 1
// baseline (1667.817 us; speedup 1.0000x reference)
//
#include <hip/hip_runtime.h>
#include <stdint.h>

#define N_ROWS 65536
#define N_COLS 256

__device__ __forceinline__ uint32_t f2key(float f) {
  uint32_t b = __float_as_uint(f);
  // monotonic transform: order of keys == order of floats
  return (b & 0x80000000u) ? ~b : (b | 0x80000000u);
}

// 64x64 tiled transpose [N_ROWS][N_COLS] -> [N_COLS][N_ROWS], fused with key transform
__global__ __launch_bounds__(256) void k_transpose_key(const float* __restrict__ in,
                                                       uint32_t* __restrict__ out) {
  __shared__ uint32_t tile[64][65];
  int tx = threadIdx.x & 63;
  int tw = threadIdx.x >> 6;  // 0..3
  int c0 = blockIdx.x * 64;
  int r0 = blockIdx.y * 64;
  for (int i = tw; i < 64; i += 4) {
    float f = in[(size_t)(r0 + i) * N_COLS + (c0 + tx)];
    tile[i][tx] = f2key(f);
  }
  __syncthreads();
  for (int i = tw; i < 64; i += 4) {
    out[(size_t)(c0 + i) * N_ROWS + (r0 + tx)] = tile[tx][i];
  }
}

// One block per column. Stable 8-bit counting-sort pass.
__global__ __launch_bounds__(1024) void k_radix_pass(const uint32_t* __restrict__ in,
                                                     uint32_t* __restrict__ out, int shift) {
  const uint32_t* src = in + (size_t)blockIdx.x * N_ROWS;
  uint32_t* dst = out + (size_t)blockIdx.x * N_ROWS;
  __shared__ uint32_t hist[256];
  __shared__ uint32_t runoff[256];
  __shared__ uint32_t waveCnt[16][256];
  int t = threadIdx.x;
  int lane = t & 63, w = t >> 6;

  if (t < 256) hist[t] = 0;
  __syncthreads();
  // phase 1: column digit histogram
  for (int i = t; i < N_ROWS; i += 1024) {
    uint32_t d = (src[i] >> shift) & 255u;
    atomicAdd(&hist[d], 1u);
  }
  __syncthreads();
  // exclusive scan of 256 bins by wave 0 (4 bins/lane + wave shfl scan)
  if (w == 0) {
    uint32_t v0 = hist[4 * lane + 0], v1 = hist[4 * lane + 1];
    uint32_t v2 = hist[4 * lane + 2], v3 = hist[4 * lane + 3];
    uint32_t s = v0 + v1 + v2 + v3;
    uint32_t inc = s;
    for (int off = 1; off < 64; off <<= 1) {
      uint32_t n = __shfl_up(inc, off);
      if (lane >= off) inc += n;
    }
    uint32_t excl = inc - s;
    runoff[4 * lane + 0] = excl;
    runoff[4 * lane + 1] = excl + v0;
    runoff[4 * lane + 2] = excl + v0 + v1;
    runoff[4 * lane + 3] = excl + v0 + v1 + v2;
  }
  __syncthreads();

  // phase 2: stable scatter, 1024-element chunks
  for (int base = 0; base < N_ROWS; base += 1024) {
    uint32_t key = src[base + t];
    uint32_t dg = (key >> shift) & 255u;
    // zero per-wave counts (16*256 entries)
    uint32_t* wc = (uint32_t*)waveCnt;
    wc[t] = 0; wc[t + 1024] = 0; wc[t + 2048] = 0; wc[t + 3072] = 0;
    __syncthreads();
    // same-digit mask within the wave via 8 ballots
    uint64_t m = ~0ULL;
#pragma unroll
    for (int b = 0; b < 8; ++b) {
      uint64_t bb = __ballot((dg >> b) & 1u);
      m &= ((dg >> b) & 1u) ? bb : ~bb;
    }
    uint32_t lower = __popcll(m & ((1ULL << lane) - 1ULL));
    if (lower == 0) waveCnt[w][dg] = __popcll(m);  // one leader per (wave,digit)
    __syncthreads();
    uint32_t pre = 0;
    for (int w2 = 0; w2 < w; ++w2) pre += waveCnt[w2][dg];
    dst[runoff[dg] + pre + lower] = key;
    __syncthreads();
    // advance running offsets by this chunk's totals
    if (t < 256) {
      uint32_t tot = 0;
#pragma unroll
      for (int w2 = 0; w2 < 16; ++w2) tot += waveCnt[w2][t];
      runoff[t] += tot;
    }
    __syncthreads();
  }
}

// Per column: merge sorted X_hat against sorted X, accumulate AD terms in f64.
__global__ __launch_bounds__(1024) void k_ad_accum(const uint32_t* __restrict__ xs,
                                                   const uint32_t* __restrict__ xh,
                                                   double* __restrict__ colsum) {
  int col = blockIdx.x;
  const uint32_t* A = xs + (size_t)col * N_ROWS;  // sorted X keys
  const uint32_t* B = xh + (size_t)col * N_ROWS;  // sorted X_hat keys
  int t = threadIdx.x;
  const int SLICE = N_ROWS / 1024;  // 64
  int i0 = t * SLICE;
  // upper_bound(A, B[i0]): first index with A[idx] > v
  uint32_t v0 = B[i0];
  int lo = 0, hi = N_ROWS;
  while (lo < hi) {
    int mid = (lo + hi) >> 1;
    if (A[mid] <= v0) lo = mid + 1; else hi = mid;
  }
  int j = lo;
  double acc = 0.0;
  for (int k = 0; k < SLICE; ++k) {
    int i = i0 + k;
    uint32_t v = B[i];
    while (j < N_ROWS && A[j] <= v) ++j;
    float u = (float)(j + 1) / 65538.0f;  // (count+1)/(N+2)
    float lu = logf(u);
    float l1 = log1pf(-u);
    float coef1 = (float)(2 * i + 1);
    float coef2 = (float)(2 * N_ROWS - 1 - 2 * i);
    acc += (double)(coef1 * lu + coef2 * l1);
  }
  __shared__ double red[1024];
  red[t] = acc;
  __syncthreads();
  for (int s = 512; s > 0; s >>= 1) {
    if (t < s) red[t] += red[t + s];
    __syncthreads();
  }
  if (t == 0) colsum[col] = red[0];
}

__global__ __launch_bounds__(256) void k_final(const double* __restrict__ colsum,
                                               float* __restrict__ out) {
  __shared__ double red[256];
  int t = threadIdx.x;
  red[t] = colsum[t];
  __syncthreads();
  for (int s = 128; s > 0; s >>= 1) {
    if (t < s) red[t] += red[t + s];
    __syncthreads();
  }
  if (t == 0) {
    double S = red[0];
    double dist = -S / ((double)N_ROWS * (double)N_COLS) - (double)N_ROWS;
    out[0] = (float)dist;
  }
}

extern "C" void kernel_launch(void* const* d_in, const int* in_sizes, int n_in,
                              void* d_out, int out_size, void* d_ws, size_t ws_size,
                              hipStream_t stream) {
  const float* X = (const float*)d_in[0];
  const float* Xh = (const float*)d_in[1];
  float* out = (float*)d_out;

  const size_t NELEM = (size_t)N_COLS * N_ROWS;  // 16.7M u32 = 64MB
  uint32_t* P0 = (uint32_t*)d_ws;       // X keys (final sorted here)
  uint32_t* P1 = P0 + NELEM;            // pong
  uint32_t* P2 = P1 + NELEM;            // X_hat keys (final sorted here)
  double* colsum = (double*)P1;         // reuse pong after both sorts

  dim3 tgrid(N_COLS / 64, N_ROWS / 64);
  k_transpose_key<<<tgrid, 256, 0, stream>>>(X, P0);
  k_transpose_key<<<tgrid, 256, 0, stream>>>(Xh, P2);

  // sort X: P0->P1->P0->P1->P0
  k_radix_pass<<<N_COLS, 1024, 0, stream>>>(P0, P1, 0);
  k_radix_pass<<<N_COLS, 1024, 0, stream>>>(P1, P0, 8);
  k_radix_pass<<<N_COLS, 1024, 0, stream>>>(P0, P1, 16);
  k_radix_pass<<<N_COLS, 1024, 0, stream>>>(P1, P0, 24);
  // sort X_hat: P2->P1->P2->P1->P2
  k_radix_pass<<<N_COLS, 1024, 0, stream>>>(P2, P1, 0);
  k_radix_pass<<<N_COLS, 1024, 0, stream>>>(P1, P2, 8);
  k_radix_pass<<<N_COLS, 1024, 0, stream>>>(P2, P1, 16);
  k_radix_pass<<<N_COLS, 1024, 0, stream>>>(P1, P2, 24);

  k_ad_accum<<<N_COLS, 1024, 0, stream>>>(P0, P2, colsum);
  k_final<<<1, 256, 0, stream>>>(colsum, out);
}

// Round 2
// 810.326 us; speedup vs baseline: 2.0582x; 2.0582x over previous
//
#include <hip/hip_runtime.h>
#include <stdint.h>

#define NR 65536
#define NC 256

__device__ __forceinline__ uint32_t f2key(float f) {
  uint32_t b = __float_as_uint(f);
  return (b & 0x80000000u) ? ~b : (b | 0x80000000u);
}

// 64x64 tiled transpose [NR][NC] -> [NC][NR], fused with key transform
__global__ __launch_bounds__(256) void k_transpose_key(const float* __restrict__ in,
                                                       uint32_t* __restrict__ out) {
  __shared__ uint32_t tile[64][65];
  int tx = threadIdx.x & 63;
  int tw = threadIdx.x >> 6;
  int c0 = blockIdx.x * 64;
  int r0 = blockIdx.y * 64;
  for (int i = tw; i < 64; i += 4) {
    float f = in[(size_t)(r0 + i) * NC + (c0 + tx)];
    tile[i][tx] = f2key(f);
  }
  __syncthreads();
  for (int i = tw; i < 64; i += 4) {
    out[(size_t)(c0 + i) * NR + (r0 + tx)] = tile[tx][i];
  }
}

// byte-0 histogram per column (for first radix pass)
__global__ __launch_bounds__(1024) void k_hist0(const uint32_t* __restrict__ keys,
                                                uint32_t* __restrict__ hist) {
  __shared__ uint32_t h[256];
  int col = blockIdx.x, t = threadIdx.x;
  if (t < 256) h[t] = 0;
  __syncthreads();
  const uint32_t* src = keys + (size_t)col * NR;
  for (int i = t; i < NR; i += 1024) atomicAdd(&h[src[i] & 255u], 1u);
  __syncthreads();
  if (t < 256) hist[col * 256 + t] = h[t];
}

// One block per column. Stable 8-bit counting-sort pass, 4 keys/thread,
// LDS digit-staged for coalesced run writes. histIn: precomputed digit
// histogram (or null -> compute via extra read). histOut: histogram of the
// NEXT byte (shift+8), accumulated for free during the scatter (or null).
__global__ __launch_bounds__(1024) void k_radix_pass(const uint32_t* __restrict__ in,
                                                     uint32_t* __restrict__ out, int shift,
                                                     const uint32_t* __restrict__ histIn,
                                                     uint32_t* __restrict__ histOut) {
  const int col = blockIdx.x;
  const uint32_t* src = in + (size_t)col * NR;
  uint32_t* dst = out + (size_t)col * NR;
  __shared__ uint32_t waveCnt[16][256];
  __shared__ uint32_t waveOff[16][256];
  __shared__ uint32_t stage[4096];
  __shared__ uint32_t runoff[256], chunkStart[256], chunkTot[256], nextHist[256];
  const int t = threadIdx.x;
  const int lane = t & 63, w = t >> 6;

  for (int i = t; i < 16 * 256; i += 1024) ((uint32_t*)waveCnt)[i] = 0;
  if (t < 256) nextHist[t] = 0;
  if (histIn) {
    if (t < 256) runoff[t] = histIn[col * 256 + t];
  } else {
    if (t < 256) runoff[t] = 0;
    __syncthreads();
    for (int i = t; i < NR; i += 1024) atomicAdd(&runoff[(src[i] >> shift) & 255u], 1u);
  }
  __syncthreads();
  if (w == 0) {  // exclusive scan runoff in place
    uint32_t v0 = runoff[4 * lane], v1 = runoff[4 * lane + 1];
    uint32_t v2 = runoff[4 * lane + 2], v3 = runoff[4 * lane + 3];
    uint32_t s = v0 + v1 + v2 + v3, inc = s;
    for (int off = 1; off < 64; off <<= 1) {
      uint32_t n = __shfl_up(inc, off);
      if (lane >= off) inc += n;
    }
    uint32_t excl = inc - s;
    runoff[4 * lane] = excl;
    runoff[4 * lane + 1] = excl + v0;
    runoff[4 * lane + 2] = excl + v0 + v1;
    runoff[4 * lane + 3] = excl + v0 + v1 + v2;
  }
  __syncthreads();

  const uint64_t ltm = (1ULL << lane) - 1ULL;
  for (int cb = 0; cb < NR; cb += 4096) {
    uint32_t key[4], dg[4], rnk[4];
#pragma unroll
    for (int k = 0; k < 4; ++k) {
      key[k] = src[cb + 256 * w + 64 * k + lane];  // element id = 256w+64k+lane
      dg[k] = (key[k] >> shift) & 255u;
    }
    // wave-local stable ranking, no block barriers
#pragma unroll
    for (int k = 0; k < 4; ++k) {
      uint32_t d = dg[k];
      uint32_t pre = waveCnt[w][d];
      uint64_t m = ~0ULL;
#pragma unroll
      for (int b = 0; b < 8; ++b) {
        uint64_t bb = __ballot((d >> b) & 1u);
        m &= ((d >> b) & 1u) ? bb : ~bb;
      }
      uint32_t lower = (uint32_t)__popcll(m & ltm);
      rnk[k] = pre + lower;
      if (lower == 0) waveCnt[w][d] = pre + (uint32_t)__popcll(m);
      __builtin_amdgcn_wave_barrier();
    }
    __syncthreads();  // 1: ranking done
    if (t < 256) {
      uint32_t run = 0;
#pragma unroll
      for (int ww = 0; ww < 16; ++ww) {
        waveOff[ww][t] = run;
        run += waveCnt[ww][t];
        waveCnt[ww][t] = 0;  // reset for next chunk
      }
      chunkTot[t] = run;
    }
    __syncthreads();  // 2: totals ready
    if (w == 0) {
      uint32_t v0 = chunkTot[4 * lane], v1 = chunkTot[4 * lane + 1];
      uint32_t v2 = chunkTot[4 * lane + 2], v3 = chunkTot[4 * lane + 3];
      uint32_t s = v0 + v1 + v2 + v3, inc = s;
      for (int off = 1; off < 64; off <<= 1) {
        uint32_t n = __shfl_up(inc, off);
        if (lane >= off) inc += n;
      }
      uint32_t excl = inc - s;
      chunkStart[4 * lane] = excl;
      chunkStart[4 * lane + 1] = excl + v0;
      chunkStart[4 * lane + 2] = excl + v0 + v1;
      chunkStart[4 * lane + 3] = excl + v0 + v1 + v2;
    }
    __syncthreads();  // 3: chunkStart ready
#pragma unroll
    for (int k = 0; k < 4; ++k)
      stage[chunkStart[dg[k]] + waveOff[w][dg[k]] + rnk[k]] = key[k];
    __syncthreads();  // 4: staged (digit-sorted within chunk)
#pragma unroll
    for (int k = 0; k < 4; ++k) {
      int p = t + 1024 * k;
      uint32_t kk = stage[p];
      uint32_t d = (kk >> shift) & 255u;
      dst[runoff[d] + (uint32_t)p - chunkStart[d]] = kk;
      if (histOut) atomicAdd(&nextHist[(kk >> (shift + 8)) & 255u], 1u);
    }
    __syncthreads();  // 5: out done (runoff reads complete)
    if (t < 256) runoff[t] += chunkTot[t];
  }
  if (histOut && t < 256) histOut[col * 256 + t] = nextHist[t];
}

// Per column: LDS-staged merge of sorted X_hat against sorted X, f64 accum.
__global__ __launch_bounds__(1024) void k_ad_accum(const uint32_t* __restrict__ xs,
                                                   const uint32_t* __restrict__ xh,
                                                   double* __restrict__ colsum) {
  constexpr int BCH = 4096, CAPA = 6144;
  __shared__ uint32_t ldsB[BCH];
  __shared__ uint32_t ldsA[CAPA];
  __shared__ int sh_jnext;
  __shared__ double red[1024];
  int col = blockIdx.x, t = threadIdx.x;
  const uint32_t* A = xs + (size_t)col * NR;
  const uint32_t* B = xh + (size_t)col * NR;
  int jb = 0;
  double acc = 0.0;
  for (int r = 0; r < NR / BCH; ++r) {
    int base = r * BCH;
#pragma unroll
    for (int k = 0; k < 4; ++k) ldsB[t + 1024 * k] = B[base + t + 1024 * k];
    int avail = min(CAPA, NR - jb);
    for (int i = t; i < avail; i += 1024) ldsA[i] = A[jb + i];
    __syncthreads();
    uint32_t v0 = ldsB[4 * t];
    int lo = 0, hi = avail;
    while (lo < hi) {  // upper_bound in window
      int mid = (lo + hi) >> 1;
      if (ldsA[mid] <= v0) lo = mid + 1; else hi = mid;
    }
    int j = lo;
    long jg = -1;  // >=0 -> switched to (rare) global-walk mode
#pragma unroll
    for (int k = 0; k < 4; ++k) {
      uint32_t v = ldsB[4 * t + k];
      if (jg < 0) {
        while (j < avail && ldsA[j] <= v) ++j;
        if (j == avail && jb + avail < NR) jg = jb + avail;
      }
      if (jg >= 0) {
        while (jg < NR && A[jg] <= v) ++jg;
      }
      int cnt = (jg >= 0) ? (int)jg : jb + j;
      int i = base + 4 * t + k;
      float u = (float)(cnt + 1) * (1.0f / 65538.0f);
      float lu = logf(u);
      float l1 = log1pf(-u);
      acc += (double)((float)(2 * i + 1) * lu + (float)(2 * NR - 1 - 2 * i) * l1);
    }
    if (t == 1023) sh_jnext = (jg >= 0) ? (int)jg : jb + j;
    __syncthreads();
    jb = sh_jnext;
  }
  red[t] = acc;
  __syncthreads();
  for (int s = 512; s > 0; s >>= 1) {
    if (t < s) red[t] += red[t + s];
    __syncthreads();
  }
  if (t == 0) colsum[col] = red[0];
}

__global__ __launch_bounds__(256) void k_final(const double* __restrict__ colsum,
                                               float* __restrict__ out) {
  __shared__ double red[256];
  int t = threadIdx.x;
  red[t] = colsum[t];
  __syncthreads();
  for (int s = 128; s > 0; s >>= 1) {
    if (t < s) red[t] += red[t + s];
    __syncthreads();
  }
  if (t == 0) {
    double S = red[0];
    double dist = -S / ((double)NR * (double)NC) - (double)NR;
    out[0] = (float)dist;
  }
}

extern "C" void kernel_launch(void* const* d_in, const int* in_sizes, int n_in,
                              void* d_out, int out_size, void* d_ws, size_t ws_size,
                              hipStream_t stream) {
  const float* X = (const float*)d_in[0];
  const float* Xh = (const float*)d_in[1];
  float* out = (float*)d_out;

  const size_t NEL = (size_t)NC * NR;        // 16.7M u32 = 64MB
  uint32_t* P0 = (uint32_t*)d_ws;            // X keys (sorted here)
  uint32_t* P1 = P0 + NEL;                   // pong
  uint32_t* P2 = P1 + NEL;                   // X_hat keys (sorted here)
  double* colsum = (double*)P1;              // reuse pong after sorts

  const size_t HIST = 256 * 256;             // u32 per hist buffer
  bool useHist = ws_size >= 3 * NEL * 4 + 4 * HIST * 4;
  uint32_t* hX0 = P2 + NEL;
  uint32_t* hX1 = hX0 + HIST;
  uint32_t* hH0 = hX1 + HIST;
  uint32_t* hH1 = hH0 + HIST;

  dim3 tgrid(NC / 64, NR / 64);
  k_transpose_key<<<tgrid, 256, 0, stream>>>(X, P0);
  k_transpose_key<<<tgrid, 256, 0, stream>>>(Xh, P2);

  if (useHist) {
    k_hist0<<<NC, 1024, 0, stream>>>(P0, hX0);
    k_hist0<<<NC, 1024, 0, stream>>>(P2, hH0);
  }
  uint32_t* nul = nullptr;
#define HI(p) (useHist ? (p) : nul)
  // sort X: P0->P1->P0->P1->P0
  k_radix_pass<<<NC, 1024, 0, stream>>>(P0, P1, 0,  HI(hX0), HI(hX1));
  k_radix_pass<<<NC, 1024, 0, stream>>>(P1, P0, 8,  HI(hX1), HI(hX0));
  k_radix_pass<<<NC, 1024, 0, stream>>>(P0, P1, 16, HI(hX0), HI(hX1));
  k_radix_pass<<<NC, 1024, 0, stream>>>(P1, P0, 24, HI(hX1), nul);
  // sort X_hat: P2->P1->P2->P1->P2
  k_radix_pass<<<NC, 1024, 0, stream>>>(P2, P1, 0,  HI(hH0), HI(hH1));
  k_radix_pass<<<NC, 1024, 0, stream>>>(P1, P2, 8,  HI(hH1), HI(hH0));
  k_radix_pass<<<NC, 1024, 0, stream>>>(P2, P1, 16, HI(hH0), HI(hH1));
  k_radix_pass<<<NC, 1024, 0, stream>>>(P1, P2, 24, HI(hH1), nul);
#undef HI

  k_ad_accum<<<NC, 1024, 0, stream>>>(P0, P2, colsum);
  k_final<<<1, 256, 0, stream>>>(colsum, out);
}

// Round 4
// 799.065 us; speedup vs baseline: 2.0872x; 1.0141x over previous
//
#include <hip/hip_runtime.h>
#include <stdint.h>
#include <math.h>

#define NR 65536
#define NC 256

__device__ __forceinline__ uint32_t f2key(float f) {
  uint32_t b = __float_as_uint(f);
  return (b & 0x80000000u) ? ~b : (b | 0x80000000u);
}

// 64x64 tiled transpose [NR][NC] -> [NC][NR], fused with key transform
__global__ __launch_bounds__(256) void k_transpose_key(const float* __restrict__ in,
                                                       uint32_t* __restrict__ out) {
  __shared__ uint32_t tile[64][65];
  int tx = threadIdx.x & 63;
  int tw = threadIdx.x >> 6;
  int c0 = blockIdx.x * 64;
  int r0 = blockIdx.y * 64;
  for (int i = tw; i < 64; i += 4)
    tile[i][tx] = f2key(in[(size_t)(r0 + i) * NC + (c0 + tx)]);
  __syncthreads();
  for (int i = tw; i < 64; i += 4)
    out[(size_t)(c0 + i) * NR + (r0 + tx)] = tile[tx][i];
}

// byte-0 histogram; arr = blockIdx.x>>8 selects X vs H
__global__ __launch_bounds__(1024) void k_hist0(const uint32_t* __restrict__ kX,
                                                const uint32_t* __restrict__ kH,
                                                uint32_t* __restrict__ hX,
                                                uint32_t* __restrict__ hH) {
  __shared__ uint32_t h[256];
  int arr = blockIdx.x >> 8, col = blockIdx.x & 255, t = threadIdx.x;
  const uint32_t* src = (arr ? kH : kX) + (size_t)col * NR;
  uint32_t* hist = (arr ? hH : hX) + col * 256;
  if (t < 256) h[t] = 0;
  __syncthreads();
  for (int i = t; i < NR; i += 1024) atomicAdd(&h[src[i] & 255u], 1u);
  __syncthreads();
  if (t < 256) hist[t] = h[t];
}

// ln table: tab[c] = { ln(c+1), ln(65537-c) }, c = 0..65536, computed in f64
__global__ __launch_bounds__(256) void k_table(float2* __restrict__ tab) {
  int v = blockIdx.x * 256 + threadIdx.x;
  if (v <= 65536) {
    float2 p;
    p.x = (float)log((double)(v + 1));
    p.y = (float)log((double)(65537 - v));
    tab[v] = p;
  }
}

// Stable 8-bit counting-sort pass; one block per (array, column).
// 3 barriers/chunk, parity-buffered runoff, register prefetch, 2 blocks/CU.
__global__ __launch_bounds__(1024, 8) void k_radix_pass(
    const uint32_t* __restrict__ sX, uint32_t* __restrict__ dXb,
    const uint32_t* __restrict__ sH, uint32_t* __restrict__ dHb, int shift,
    const uint32_t* __restrict__ hInX, uint32_t* __restrict__ hOutX,
    const uint32_t* __restrict__ hInH, uint32_t* __restrict__ hOutH) {
  const int arr = blockIdx.x >> 8;
  const int col = blockIdx.x & 255;
  const uint32_t* src = (arr ? sH : sX) + (size_t)col * NR;
  uint32_t* dst = (arr ? dHb : dXb) + (size_t)col * NR;
  const uint32_t* histIn = arr ? hInH : hInX;
  uint32_t* histOut = arr ? hOutH : hOutX;

  __shared__ uint32_t waveCnt[16][256];
  __shared__ uint32_t waveOff[16][256];
  __shared__ uint32_t stage[4096];
  __shared__ uint32_t runoffP[2][256];
  __shared__ uint32_t chunkStart[256];
  __shared__ uint32_t nextHist[256];

  const int t = threadIdx.x;
  const int lane = t & 63, w = t >> 6;
  const uint64_t ltm = (1ULL << lane) - 1ULL;

  for (int i = t; i < 16 * 256; i += 1024) ((uint32_t*)waveCnt)[i] = 0;
  if (t < 256) nextHist[t] = 0;
  if (histIn) {
    if (t < 256) runoffP[0][t] = histIn[col * 256 + t];
  } else {
    if (t < 256) runoffP[0][t] = 0;
    __syncthreads();
    for (int i = t; i < NR; i += 1024)
      atomicAdd(&runoffP[0][(src[i] >> shift) & 255u], 1u);
  }
  __syncthreads();
  if (w == 0) {  // exclusive scan of digit hist into runoffP[0]; d = lane+64q
    uint32_t carry = 0;
#pragma unroll
    for (int q = 0; q < 4; ++q) {
      int d = lane + 64 * q;
      uint32_t v = runoffP[0][d];
      uint32_t inc = v;
      for (int off = 1; off < 64; off <<= 1) {
        uint32_t nn = __shfl_up(inc, off);
        if (lane >= off) inc += nn;
      }
      runoffP[0][d] = carry + inc - v;
      carry += __shfl(inc, 63);
    }
  }
  __syncthreads();

  int par = 0;
  uint32_t key[4];
#pragma unroll
  for (int k = 0; k < 4; ++k) key[k] = src[256 * w + 64 * k + lane];

  for (int cb = 0; cb < NR; cb += 4096) {
    uint32_t nxt[4];
    const bool more = (cb + 4096) < NR;
    if (more) {
#pragma unroll
      for (int k = 0; k < 4; ++k)
        nxt[k] = src[cb + 4096 + 256 * w + 64 * k + lane];
    }
    // wave-local stable ranking (element id = cb + 256w + 64k + lane)
    uint32_t rnk[4];
#pragma unroll
    for (int k = 0; k < 4; ++k) {
      uint32_t d = (key[k] >> shift) & 255u;
      uint32_t pre = waveCnt[w][d];
      uint64_t m = ~0ULL;
#pragma unroll
      for (int b = 0; b < 8; ++b) {
        uint64_t bb = __ballot((d >> b) & 1u);
        m &= ((d >> b) & 1u) ? bb : ~bb;
      }
      uint32_t lower = (uint32_t)__popcll(m & ltm);
      rnk[k] = pre + lower;
      if (lower == 0) waveCnt[w][d] = pre + (uint32_t)__popcll(m);
      __builtin_amdgcn_wave_barrier();
    }
    __syncthreads();  // B1: ranking done (also fences prev chunk's scatter)
    if (w == 0) {     // megaphase: waveOff + totals + scan + runoff advance
      uint32_t carry = 0;
#pragma unroll
      for (int q = 0; q < 4; ++q) {
        int d = lane + 64 * q;
        uint32_t run = 0;
#pragma unroll
        for (int ww = 0; ww < 16; ++ww) {
          waveOff[ww][d] = run;
          run += waveCnt[ww][d];
          waveCnt[ww][d] = 0;
        }
        runoffP[par ^ 1][d] = runoffP[par][d] + run;
        uint32_t inc = run;
        for (int off = 1; off < 64; off <<= 1) {
          uint32_t nn = __shfl_up(inc, off);
          if (lane >= off) inc += nn;
        }
        chunkStart[d] = carry + inc - run;
        carry += __shfl(inc, 63);
      }
    }
    __syncthreads();  // B2: chunkStart/waveOff ready
#pragma unroll
    for (int k = 0; k < 4; ++k) {
      uint32_t d = (key[k] >> shift) & 255u;
      stage[chunkStart[d] + waveOff[w][d] + rnk[k]] = key[k];
    }
    __syncthreads();  // B3: staged digit-sorted
#pragma unroll
    for (int k = 0; k < 4; ++k) {
      int p = t + 1024 * k;
      uint32_t kk = stage[p];
      uint32_t d = (kk >> shift) & 255u;
      dst[runoffP[par][d] + (uint32_t)p - chunkStart[d]] = kk;
    }
    if (histOut) {
#pragma unroll
      for (int k = 0; k < 4; ++k) {
        uint32_t kk = stage[t + 1024 * k];
        atomicAdd(&nextHist[(kk >> (shift + 8)) & 255u], 1u);
      }
    }
    par ^= 1;
    if (more) {
#pragma unroll
      for (int k = 0; k < 4; ++k) key[k] = nxt[k];
    }
  }
  if (histOut) {
    __syncthreads();
    if (t < 256) histOut[col * 256 + t] = nextHist[t];
  }
}

// Per (col,half) start count: seed[2*col+half] = #{A_col <= B_col[half*NR/2]}
__global__ __launch_bounds__(64) void k_seed(const uint32_t* __restrict__ xs,
                                             const uint32_t* __restrict__ xh,
                                             uint32_t* __restrict__ seed) {
  int id = blockIdx.x * 64 + threadIdx.x;  // 0..511
  int col = id >> 1, half = id & 1;
  const uint32_t* A = xs + (size_t)col * NR;
  uint32_t v = xh[(size_t)col * NR + half * (NR / 2)];
  int lo = 0, hi = NR;
  while (lo < hi) {
    int mid = (lo + hi) >> 1;
    if (A[mid] <= v) lo = mid + 1; else hi = mid;
  }
  seed[id] = (uint32_t)lo;
}

// LDS-staged merge + AD accumulation via ln-table gathers.
// term = (2i+1)*ln(c+1) + (2N-1-2i)*ln(65537-c); constants fold into k_final.
__global__ __launch_bounds__(1024, 8) void k_ad_accum(const uint32_t* __restrict__ xs,
                                                      const uint32_t* __restrict__ xh,
                                                      const uint32_t* __restrict__ seed,
                                                      const float2* __restrict__ tab,
                                                      double* __restrict__ colsum) {
  constexpr int BCH = 4096, CAPA = 6144;
  __shared__ uint32_t ldsB[BCH];
  __shared__ uint32_t ldsA[CAPA];
  __shared__ int sh_jnext;
  __shared__ double red[1024];
  const int bid = blockIdx.x, col = bid >> 1, half = bid & 1, t = threadIdx.x;
  const uint32_t* A = xs + (size_t)col * NR;
  const uint32_t* B = xh + (size_t)col * NR;
  int jb = (int)seed[bid];
  double acc = 0.0;
  const int base0 = half * (NR / 2);
  for (int r = 0; r < (NR / 2) / BCH; ++r) {
    int base = base0 + r * BCH;
#pragma unroll
    for (int k = 0; k < 4; ++k) ldsB[t + 1024 * k] = B[base + t + 1024 * k];
    int avail = min(CAPA, NR - jb);
    for (int i = t; i < avail; i += 1024) ldsA[i] = A[jb + i];
    __syncthreads();
    uint4 bv = ((const uint4*)ldsB)[t];  // ds_read_b128, conflict-free
    uint32_t be[4] = {bv.x, bv.y, bv.z, bv.w};
    int lo = 0, hi = avail;
    while (lo < hi) {
      int mid = (lo + hi) >> 1;
      if (ldsA[mid] <= be[0]) lo = mid + 1; else hi = mid;
    }
    int j = lo;
    long jg = -1;  // rare window-overflow fallback (global walk)
#pragma unroll
    for (int k = 0; k < 4; ++k) {
      uint32_t v = be[k];
      if (jg < 0) {
        while (j < avail && ldsA[j] <= v) ++j;
        if (j == avail && jb + avail < NR) jg = jb + avail;
      }
      if (jg >= 0) {
        while (jg < NR && A[jg] <= v) ++jg;
      }
      int cnt = (jg >= 0) ? (int)jg : jb + j;
      int i = base + 4 * t + k;
      float2 p = tab[cnt];  // {ln(cnt+1), ln(65537-cnt)} in 0.5-ulp f32
      acc += (double)((float)(2 * i + 1) * p.x + (float)(2 * NR - 1 - 2 * i) * p.y);
    }
    if (t == 1023) sh_jnext = (jg >= 0) ? (int)jg : jb + j;
    __syncthreads();
    jb = sh_jnext;
  }
  red[t] = acc;
  __syncthreads();
  for (int s = 512; s > 0; s >>= 1) {
    if (t < s) red[t] += red[t + s];
    __syncthreads();
  }
  if (t == 0) colsum[bid] = red[0];
}

__global__ __launch_bounds__(512) void k_final(const double* __restrict__ colsum,
                                               float* __restrict__ out) {
  __shared__ double red[512];
  int t = threadIdx.x;
  red[t] = colsum[t];
  __syncthreads();
  for (int s = 256; s > 0; s >>= 1) {
    if (t < s) red[t] += red[t + s];
    __syncthreads();
  }
  if (t == 0) {
    double total = red[0];
    // dist = -total/(N*D) + 2N*ln(N+2) - N   (ln-table constants folded)
    double dist = -total / ((double)NR * (double)NC)
                  + 2.0 * (double)NR * log(65538.0) - (double)NR;
    out[0] = (float)dist;
  }
}

extern "C" void kernel_launch(void* const* d_in, const int* in_sizes, int n_in,
                              void* d_out, int out_size, void* d_ws, size_t ws_size,
                              hipStream_t stream) {
  const float* X = (const float*)d_in[0];
  const float* Xh = (const float*)d_in[1];
  float* out = (float*)d_out;

  const size_t NEL = (size_t)NC * NR;  // 16.7M u32 = 64MB
  const size_t HIST = 256 * 256;
  uint32_t* P0 = (uint32_t*)d_ws;  // X keys (sorted here)
  uint32_t* P1 = P0 + NEL;         // pong (dead after sorts)
  uint32_t* P2 = P1 + NEL;         // X_hat keys (sorted here)
  // carved from dead P1 (no overlap: colsum 4KB @0, seeds 2KB @16KB, tab 524KB @32KB)
  double* colsum = (double*)P1;
  uint32_t* seeds = P1 + 4096;
  float2* tab = (float2*)(P1 + 8192);

  dim3 tg(NC / 64, NR / 64);
  k_transpose_key<<<tg, 256, 0, stream>>>(X, P0);
  k_transpose_key<<<tg, 256, 0, stream>>>(Xh, P2);

  uint32_t* nul = nullptr;
  bool fused = ws_size >= (4 * NEL + 4 * HIST + 4096) * sizeof(uint32_t);
  if (fused) {
    uint32_t* P3 = P2 + NEL;
    uint32_t* hX0 = P3 + NEL;
    uint32_t* hX1 = hX0 + HIST;
    uint32_t* hH0 = hX1 + HIST;
    uint32_t* hH1 = hH0 + HIST;
    k_hist0<<<512, 1024, 0, stream>>>(P0, P2, hX0, hH0);
    k_radix_pass<<<512, 1024, 0, stream>>>(P0, P1, P2, P3, 0,  hX0, hX1, hH0, hH1);
    k_radix_pass<<<512, 1024, 0, stream>>>(P1, P0, P3, P2, 8,  hX1, hX0, hH1, hH0);
    k_radix_pass<<<512, 1024, 0, stream>>>(P0, P1, P2, P3, 16, hX0, hX1, hH0, hH1);
    k_radix_pass<<<512, 1024, 0, stream>>>(P1, P0, P3, P2, 24, hX1, nul, hH1, nul);
  } else {
    bool useHist = ws_size >= (3 * NEL + 4 * HIST) * sizeof(uint32_t);
    uint32_t* hX0 = P2 + NEL;
    uint32_t* hX1 = hX0 + HIST;
    uint32_t* hH0 = hX1 + HIST;
    uint32_t* hH1 = hH0 + HIST;
    if (useHist) {
      k_hist0<<<256, 1024, 0, stream>>>(P0, P0, hX0, hX0);
      k_hist0<<<256, 1024, 0, stream>>>(P2, P2, hH0, hH0);
    }
#define HI(p) (useHist ? (p) : nul)
    k_radix_pass<<<256, 1024, 0, stream>>>(P0, P1, P0, P1, 0,  HI(hX0), HI(hX1), nul, nul);
    k_radix_pass<<<256, 1024, 0, stream>>>(P1, P0, P1, P0, 8,  HI(hX1), HI(hX0), nul, nul);
    k_radix_pass<<<256, 1024, 0, stream>>>(P0, P1, P0, P1, 16, HI(hX0), HI(hX1), nul, nul);
    k_radix_pass<<<256, 1024, 0, stream>>>(P1, P0, P1, P0, 24, HI(hX1), nul, nul, nul);
    k_radix_pass<<<256, 1024, 0, stream>>>(P2, P1, P2, P1, 0,  HI(hH0), HI(hH1), nul, nul);
    k_radix_pass<<<256, 1024, 0, stream>>>(P1, P2, P1, P2, 8,  HI(hH1), HI(hH0), nul, nul);
    k_radix_pass<<<256, 1024, 0, stream>>>(P2, P1, P2, P1, 16, HI(hH0), HI(hH1), nul, nul);
    k_radix_pass<<<256, 1024, 0, stream>>>(P1, P2, P1, P2, 24, HI(hH1), nul, nul, nul);
#undef HI
  }

  k_table<<<257, 256, 0, stream>>>(tab);
  k_seed<<<8, 64, 0, stream>>>(P0, P2, seeds);
  k_ad_accum<<<512, 1024, 0, stream>>>(P0, P2, seeds, tab, colsum);
  k_final<<<1, 512, 0, stream>>>(colsum, out);
}